// Round 14
// baseline (10290.160 us; speedup 1.0000x reference)
//
#include <hip/hip_runtime.h>
#include <stdint.h>

#define BDIM 64
#define TDIM 512
#define EDIM 512
#define HDIM 512

typedef __attribute__((ext_vector_type(8))) short bf16x8;
typedef __attribute__((ext_vector_type(4))) float f32x4;
typedef __attribute__((ext_vector_type(4))) unsigned int u32x4;
typedef __attribute__((ext_vector_type(4))) unsigned short u16x4;
typedef unsigned long long u64t;

static __device__ __forceinline__ unsigned short f2bf(float f) {
  union { float f; uint32_t u; } c; c.f = f;
  uint32_t u = c.u;
  uint32_t r = u + 0x7fffu + ((u >> 16) & 1u);
  return (unsigned short)(r >> 16);
}
static __device__ __forceinline__ float bf2f(unsigned short s) {
  union { uint32_t u; float f; } c; c.u = ((uint32_t)s) << 16;
  return c.f;
}

// swizzle for 1KB-row tiles (512 bf16 per row)
#define SWZ(row, byteInRow) ((((row)*1024) + (byteInRow)) ^ ((((row)&7))<<4))
// swizzle for 128B-row tiles (64 bf16 per row)
#define SWZA(row, byteInRow) ((((row)*128) + (byteInRow)) ^ ((((row)&7))<<4))

// ---------------- small utility kernels ----------------

__global__ void sentinel_kern(float* out, int n) {
  for (int i = blockIdx.x * blockDim.x + threadIdx.x; i < n; i += gridDim.x * blockDim.x)
    out[i] = -12345.0f;
}

__global__ void conv_w(const float* __restrict__ Wz, const float* __restrict__ Wr,
                       const float* __restrict__ Wh,
                       unsigned short* __restrict__ Wxb, unsigned short* __restrict__ Whb) {
  int idx = blockIdx.x * 256 + threadIdx.x;
  if (idx >= 3 * 512 * 1024) return;
  int g = idx >> 19;
  int rem = idx & 524287;
  int j = rem >> 10, k = rem & 1023;
  const float* W = (g == 0) ? Wz : (g == 1) ? Wr : Wh;
  unsigned short b = f2bf(W[(size_t)j * 1024 + k]);
  if (k < 512) Wxb[((size_t)g * 512 + j) * 512 + k] = b;
  else         Whb[((size_t)g * 512 + j) * 512 + (k - 512)] = b;
}

__global__ void conv_x(const float* __restrict__ x, unsigned short* __restrict__ xb, int n4) {
  for (int i = blockIdx.x * blockDim.x + threadIdx.x; i < n4; i += gridDim.x * blockDim.x) {
    f32x4 v = ((const f32x4*)x)[i];
    u16x4 o;
    o[0] = f2bf(v[0]); o[1] = f2bf(v[1]); o[2] = f2bf(v[2]); o[3] = f2bf(v[3]);
    ((u16x4*)xb)[i] = o;
  }
}

__global__ void add_out(float* __restrict__ out, const float* __restrict__ Hb, int n4) {
  for (int i = blockIdx.x * blockDim.x + threadIdx.x; i < n4; i += gridDim.x * blockDim.x) {
    f32x4 a = ((const f32x4*)out)[i];
    f32x4 b = ((const f32x4*)Hb)[i];
    ((f32x4*)out)[i] = a + b;
  }
}

// ---------------- phase A: G = x @ Wx^T + bias (bf16 out) ----------------

__global__ __launch_bounds__(256, 2)
void gru_xproj(const unsigned short* __restrict__ xb,
               const unsigned short* __restrict__ Wxb,
               const float* __restrict__ bz, const float* __restrict__ br,
               const float* __restrict__ bh,
               unsigned short* __restrict__ Gb) {
  __shared__ __align__(16) unsigned short lA[128 * 64];
  __shared__ __align__(16) unsigned short lB[128 * 64];
  const int tid = threadIdx.x;
  const int m0 = blockIdx.x * 128;
  const int n0 = blockIdx.y * 128;
  const int w = tid >> 6, lane = tid & 63, cl = lane & 15, q = lane >> 4;
  const int wr = w >> 1, wc = w & 1;
  f32x4 acc[4][4];
#pragma unroll
  for (int i = 0; i < 4; i++)
#pragma unroll
    for (int j = 0; j < 4; j++) acc[i][j] = (f32x4){0.f, 0.f, 0.f, 0.f};

  for (int ko = 0; ko < 8; ko++) {
    int k0 = ko * 64;
#pragma unroll
    for (int cc = 0; cc < 4; cc++) {
      int qq = tid * 4 + cc;
      int row = qq >> 3, kc = qq & 7;
      u32x4 va = *(const u32x4*)(xb + ((size_t)(m0 + row) * EDIM + k0 + kc * 8));
      *(u32x4*)((char*)lA + SWZA(row, kc * 16)) = va;
      u32x4 vb = *(const u32x4*)(Wxb + ((size_t)(n0 + row) * EDIM + k0 + kc * 8));
      *(u32x4*)((char*)lB + SWZA(row, kc * 16)) = vb;
    }
    __syncthreads();
#pragma unroll
    for (int ks = 0; ks < 2; ks++) {
      bf16x8 af[4], bfv[4];
#pragma unroll
      for (int i = 0; i < 4; i++) {
        int rl = wr * 64 + i * 16 + cl;
        af[i] = *(const bf16x8*)((char*)lA + SWZA(rl, ks * 64 + q * 16));
      }
#pragma unroll
      for (int j = 0; j < 4; j++) {
        int rl = wc * 64 + j * 16 + cl;
        bfv[j] = *(const bf16x8*)((char*)lB + SWZA(rl, ks * 64 + q * 16));
      }
#pragma unroll
      for (int i = 0; i < 4; i++)
#pragma unroll
        for (int j = 0; j < 4; j++)
          acc[i][j] = __builtin_amdgcn_mfma_f32_16x16x32_bf16(af[i], bfv[j], acc[i][j], 0, 0, 0);
    }
    __syncthreads();
  }
  const int g = n0 >> 9;
  const float* bias = (g == 0) ? bz : (g == 1) ? br : bh;
#pragma unroll
  for (int i = 0; i < 4; i++) {
#pragma unroll
    for (int j = 0; j < 4; j++) {
      int n = n0 + wc * 64 + j * 16 + cl;
      float bv = bias[n & 511];
#pragma unroll
      for (int ii = 0; ii < 4; ii++) {
        int m = m0 + wr * 64 + i * 16 + q * 4 + ii;
        Gb[(size_t)m * 1536 + n] = f2bf(acc[i][j][ii] + bv);
      }
    }
  }
}

// ---------------- persistent recurrence (R12 + self-validating exchange) ----
// 128 wgs: gid = bid&7 (dir = gid>>2, bg = gid&3); cg = bid>>3, cols j0=cg*32.
// Exchange buffers are [parity][dir][bg][row16][cg16] lines of 128B; each 8B
// unit is an atomic {seq<<32 | 2xbf16-pair}. A consumer load that sees
// seq==expected atomically holds this step's data -> no separate flag, no
// producer drain, no stage-after-flag round-trip. Tags: h(s) -> s+1,
// rh(s) -> s; slab parity = producing step & 1; slabs zeroed per launch.

__global__ __launch_bounds__(256, 1)
void gru_persist(const unsigned short* __restrict__ Gb,
                 const float* __restrict__ h0,
                 char* __restrict__ Hs2,              // 512KB tagged slab (h)
                 char* __restrict__ RHs2,             // 512KB tagged slab (r*h)
                 float* __restrict__ outp,
                 float* __restrict__ Hb,
                 const unsigned short* __restrict__ Whb) {
  __shared__ __align__(16) unsigned short lds_w[6 * 16 * 512];   // 96KB
  __shared__ __align__(16) unsigned short lds_ah[16 * 512];      // 16KB
  __shared__ __align__(16) unsigned short lds_arh[16 * 512];     // 16KB
  __shared__ float lds_hprev[16 * 32];                            // 2KB

  const int tid = threadIdx.x;
  const int bid = blockIdx.x;
  const int gid = bid & 7;
  const int cg = bid >> 3;
  const int dir = gid >> 2;
  const int bg = gid & 3;
  const int j0 = cg * 32;
  const int w = tid >> 6;
  const int lane = tid & 63;
  const int c = lane & 15;
  const int q = lane >> 4;

  // line offset within a slab: [par][dir][bg][row][cgi] * 128B
  auto lineoff = [&](int par, int row, int cgi) -> size_t {
    return ((((size_t)par * 2 + dir) * 4 + bg) * 16 + row) * 16 * 128 + (size_t)cgi * 128;
  };

  // ---- one-time: weight LDS tiles (nt = gate*2+sub) ----
  for (int qk = tid; qk < 6144; qk += 256) {
    int nt = qk >> 10;
    int cin = qk & 1023;
    int col = cin & 15;
    int kc = cin >> 4;
    int g = nt >> 1, sub2 = nt & 1;
    int jglob = j0 + sub2 * 16 + col;
    u32x4 v = *(const u32x4*)(Whb + (((size_t)g * 512 + jglob) * 512 + kc * 8));
    *(u32x4*)((char*)lds_w + nt * 16384 + SWZ(col, kc * 16)) = v;
  }

  // ---- init hprev (fp32, local cols) + publish tagged h0 (par 0, tag 1) ----
  {
    int row = tid >> 4, jl2 = (tid & 15) * 2;
    int b = bg * 16 + row;
    float v0 = h0[(size_t)b * HDIM + j0 + jl2];
    float v1 = h0[(size_t)b * HDIM + j0 + jl2 + 1];
    lds_hprev[row * 32 + jl2] = v0;
    lds_hprev[row * 32 + jl2 + 1] = v1;
    unsigned int pk = (unsigned int)f2bf(v0) | ((unsigned int)f2bf(v1) << 16);
    u64t unit = ((u64t)1u << 32) | (u64t)pk;
    __hip_atomic_store((u64t*)(Hs2 + lineoff(0, row, cg) + (size_t)(tid & 15) * 8),
                       unit, __ATOMIC_RELAXED, __HIP_MEMORY_SCOPE_AGENT);
  }
  __syncthreads();

  // ---- fused poll+stage: wait until all 16 units of my line carry `expect`,
  //      block-wide AND across all 256 lines, then unpack into LDS ----
  auto pollstage = [&](const char* slab, int par, unsigned expect,
                       unsigned short* dstLds) {
    int row = tid >> 4, seg = tid & 15;
    const char* lb = slab + lineoff(par, row, seg);
    u64t v[16];
    while (true) {
      bool ok = true;
#pragma unroll
      for (int k = 0; k < 16; k++) {
        v[k] = __hip_atomic_load((const u64t*)(lb + k * 8),
                                 __ATOMIC_RELAXED, __HIP_MEMORY_SCOPE_AGENT);
        ok &= ((unsigned)(v[k] >> 32) == expect);
      }
      if (__syncthreads_and((int)ok)) break;
      __builtin_amdgcn_s_sleep(1);
    }
    char* dst = (char*)dstLds;
#pragma unroll
    for (int k = 0; k < 8; k++) {
      u64t dd = (u64t)(unsigned)v[2 * k] | ((u64t)(unsigned)v[2 * k + 1] << 32);
      *(u64t*)(dst + SWZ(row, seg * 64 + k * 8)) = dd;
    }
    __syncthreads();
  };

  const int sub = w & 1;
  const int jn = j0 + sub * 16 + c;
  const int gateA = (w < 2) ? 0 : 1;

  for (int s = 1; s <= TDIM; s++) {
    int t = dir ? (TDIM - s) : (s - 1);

    // ---- prefetch G values for this step (plain cached loads) ----
    f32x4 gA, gC;
#pragma unroll
    for (int i = 0; i < 4; i++) {
      int b = bg * 16 + q * 4 + i;
      size_t mrow = (size_t)b * TDIM + t;
      size_t giA = (mrow * 3 + gateA) * HDIM + jn;
      gA[i] = bf2f(Gb[giA]);
      if (w < 2) {
        size_t giC = (mrow * 3 + 2) * HDIM + jn;
        gC[i] = bf2f(Gb[giC]);
      }
    }

    // ---- exchange-in h(s-1): tag s, parity (s-1)&1 ----
    pollstage(Hs2, (s - 1) & 1, (unsigned)s, lds_ah);

    // ---- P1: wave w computes tile nt=w (z: 0,1 ; r: 2,3), K=512 ----
    f32x4 a0 = (f32x4){0.f,0.f,0.f,0.f}, a1 = (f32x4){0.f,0.f,0.f,0.f};
    f32x4 a2 = (f32x4){0.f,0.f,0.f,0.f}, a3 = (f32x4){0.f,0.f,0.f,0.f};
    {
      const char* wb = (const char*)lds_w + w * 16384;
      const char* ab = (const char*)lds_ah;
#pragma unroll
      for (int ks = 0; ks < 4; ks++) {
#pragma unroll
        for (int p = 0; p < 4; p++) {
          int kb = (ks * 4 + p) * 64 + q * 16;
          bf16x8 af = *(const bf16x8*)(ab + SWZ(c, kb));
          bf16x8 bfv = *(const bf16x8*)(wb + SWZ(c, kb));
          if (p == 0) a0 = __builtin_amdgcn_mfma_f32_16x16x32_bf16(af, bfv, a0, 0, 0, 0);
          else if (p == 1) a1 = __builtin_amdgcn_mfma_f32_16x16x32_bf16(af, bfv, a1, 0, 0, 0);
          else if (p == 2) a2 = __builtin_amdgcn_mfma_f32_16x16x32_bf16(af, bfv, a2, 0, 0, 0);
          else a3 = __builtin_amdgcn_mfma_f32_16x16x32_bf16(af, bfv, a3, 0, 0, 0);
        }
      }
    }
    f32x4 acc = (a0 + a1) + (a2 + a3);
    f32x4 zreg;
    if (w < 2) {
#pragma unroll
      for (int i = 0; i < 4; i++) {
        float pre = acc[i] + gA[i];
        pre = fminf(fmaxf(pre, -30.f), 30.f);
        zreg[i] = 1.f / (1.f + __expf(-pre));
      }
    } else {
      // r pointwise + tagged publish of r*h (8B self-validating units)
      float rhv[4];
#pragma unroll
      for (int i = 0; i < 4; i++) {
        int row = q * 4 + i;
        float pre = acc[i] + gA[i];
        pre = fminf(fmaxf(pre, -30.f), 30.f);
        float sg = 1.f / (1.f + __expf(-pre));
        rhv[i] = sg * lds_hprev[row * 32 + sub * 16 + c];
      }
#pragma unroll
      for (int i = 0; i < 4; i++) {
        float oth = __shfl_xor(rhv[i], 1);
        if (!(c & 1)) {
          int row = q * 4 + i;
          unsigned int pk = (unsigned int)f2bf(rhv[i]) | ((unsigned int)f2bf(oth) << 16);
          u64t unit = ((u64t)(unsigned)s << 32) | (u64t)pk;
          __hip_atomic_store(
              (u64t*)(RHs2 + lineoff(s & 1, row, cg) + (size_t)(sub * 8 + (c >> 1)) * 8),
              unit, __ATOMIC_RELAXED, __HIP_MEMORY_SCOPE_AGENT);
        }
      }
    }

    // ---- exchange-in r*h(s): tag s, parity s&1 ----
    pollstage(RHs2, s & 1, (unsigned)s, lds_arh);

    // ---- P2: waves 0,1 compute h~ tiles (nt = 4+sub), blend, publish ----
    float hn[4];
    if (w < 2) {
      f32x4 b0 = (f32x4){0.f,0.f,0.f,0.f}, b1 = (f32x4){0.f,0.f,0.f,0.f};
      f32x4 b2 = (f32x4){0.f,0.f,0.f,0.f}, b3 = (f32x4){0.f,0.f,0.f,0.f};
      const char* wb = (const char*)lds_w + (4 + sub) * 16384;
      const char* ab = (const char*)lds_arh;
#pragma unroll
      for (int ks = 0; ks < 4; ks++) {
#pragma unroll
        for (int p = 0; p < 4; p++) {
          int kb = (ks * 4 + p) * 64 + q * 16;
          bf16x8 af = *(const bf16x8*)(ab + SWZ(c, kb));
          bf16x8 bfv = *(const bf16x8*)(wb + SWZ(c, kb));
          if (p == 0) b0 = __builtin_amdgcn_mfma_f32_16x16x32_bf16(af, bfv, b0, 0, 0, 0);
          else if (p == 1) b1 = __builtin_amdgcn_mfma_f32_16x16x32_bf16(af, bfv, b1, 0, 0, 0);
          else if (p == 2) b2 = __builtin_amdgcn_mfma_f32_16x16x32_bf16(af, bfv, b2, 0, 0, 0);
          else b3 = __builtin_amdgcn_mfma_f32_16x16x32_bf16(af, bfv, b3, 0, 0, 0);
        }
      }
      f32x4 acc2 = (b0 + b1) + (b2 + b3);
#pragma unroll
      for (int i = 0; i < 4; i++) {
        int row = q * 4 + i;
        float pre = acc2[i] + gC[i];
        pre = fminf(fmaxf(pre, -15.f), 15.f);
        float e2 = __expf(2.f * pre);
        float th = (e2 - 1.f) / (e2 + 1.f);
        float hp = lds_hprev[row * 32 + sub * 16 + c];
        float z = zreg[i];
        hn[i] = hp + z * (th - hp);
        lds_hprev[row * 32 + sub * 16 + c] = hn[i];
      }
      // tagged publish of h(s): tag s+1, parity s&1
#pragma unroll
      for (int i = 0; i < 4; i++) {
        float oth = __shfl_xor(hn[i], 1);
        if (!(c & 1)) {
          int row = q * 4 + i;
          unsigned int pk = (unsigned int)f2bf(hn[i]) | ((unsigned int)f2bf(oth) << 16);
          u64t unit = ((u64t)(unsigned)(s + 1) << 32) | (u64t)pk;
          __hip_atomic_store(
              (u64t*)(Hs2 + lineoff(s & 1, row, cg) + (size_t)(sub * 8 + (c >> 1)) * 8),
              unit, __ATOMIC_RELAXED, __HIP_MEMORY_SCOPE_AGENT);
        }
      }
      // outp stores (fire-and-forget; drained by later waitcnts)
      float* op = dir ? Hb : outp;
#pragma unroll
      for (int i = 0; i < 4; i++) {
        int b = bg * 16 + q * 4 + i;
        op[((size_t)b * TDIM + t) * HDIM + jn] = hn[i];
      }
    }
  }
}

// ---------------- host ----------------

extern "C" void kernel_launch(void* const* d_in, const int* in_sizes, int n_in,
                              void* d_out, int out_size, void* d_ws, size_t ws_size,
                              hipStream_t stream) {
  (void)in_sizes; (void)n_in;
  const float* x  = (const float*)d_in[0];
  const float* h0 = (const float*)d_in[1];
  const float* Wz = (const float*)d_in[2];
  const float* bz = (const float*)d_in[3];
  const float* Wr = (const float*)d_in[4];
  const float* br = (const float*)d_in[5];
  const float* Wh = (const float*)d_in[6];
  const float* bh = (const float*)d_in[7];
  float* outp = (float*)d_out;

  const size_t szG    = (size_t)32768 * 1536 * 2;       // bf16 G
  const size_t szXb   = (size_t)BDIM * TDIM * EDIM * 2;
  const size_t szW    = (size_t)3 * 512 * 512 * 2;
  const size_t szHb   = (size_t)BDIM * TDIM * HDIM * 4;
  const size_t szSlab = (size_t)2 * 2 * 4 * 16 * 16 * 128;   // 512KB tagged slab
  const size_t fixed  = szXb + 2 * szW + szHb + 2 * szSlab + 16384;

  if (ws_size < fixed + szG) {
    sentinel_kern<<<256, 256, 0, stream>>>(outp, out_size);
    return;
  }

  size_t off = 0;
  char* base = (char*)d_ws;
  auto alloc = [&](size_t sz) { char* p = base + off; off = (off + sz + 255) & ~(size_t)255; return p; };
  unsigned short* Gb   = (unsigned short*)alloc(szG);
  unsigned short* xb   = (unsigned short*)alloc(szXb);
  unsigned short* Wxb  = (unsigned short*)alloc(szW);
  unsigned short* Whb  = (unsigned short*)alloc(szW);
  float*          Hbuf = (float*)alloc(szHb);
  char*           Hs2  = (char*)alloc(szSlab);
  char*           RHs2 = (char*)alloc(szSlab);

  hipMemsetAsync(Hs2, 0, szSlab, stream);
  hipMemsetAsync(RHs2, 0, szSlab, stream);
  conv_w<<<(3 * 512 * 1024 + 255) / 256, 256, 0, stream>>>(Wz, Wr, Wh, Wxb, Whb);
  conv_x<<<2048, 256, 0, stream>>>(x, xb, (BDIM * TDIM * EDIM) / 4);
  gru_xproj<<<dim3(256, 12), 256, 0, stream>>>(xb, Wxb, bz, br, bh, Gb);
  gru_persist<<<128, 256, 0, stream>>>(Gb, h0, Hs2, RHs2, outp, Hbuf, Whb);
  add_out<<<2048, 256, 0, stream>>>(outp, Hbuf, (BDIM * TDIM * HDIM) / 4);
  hipMemcpyAsync(outp + (size_t)BDIM * TDIM * HDIM, h0,
                 (size_t)BDIM * HDIM * sizeof(float), hipMemcpyDeviceToDevice, stream);
}